// Round 8
// baseline (393.859 us; speedup 1.0000x reference)
//
#include <hip/hip_runtime.h>
#include <stdint.h>

typedef unsigned short u16;
typedef __attribute__((ext_vector_type(8))) short bf16x8;   // 8 bf16 = 4 VGPRs (MFMA A/B frag)
typedef __attribute__((ext_vector_type(4))) float f32x4;    // MFMA C/D frag

#define KSCALE (0.17677669529663687f / 512.0f)

__device__ __forceinline__ u16 f2b(float f) {
  unsigned u = __float_as_uint(f);
  unsigned r = (u + 0x7fffu + ((u >> 16) & 1u)) >> 16;  // RNE
  return (u16)r;
}
__device__ __forceinline__ float b2f(u16 s) { return __uint_as_float(((unsigned)s) << 16); }

// async global->LDS, 16B per lane; LDS dest = wave-uniform base + lane*16
__device__ __forceinline__ void async16(const void* g, void* l) {
  __builtin_amdgcn_global_load_lds((const __attribute__((address_space(1))) unsigned int*)g,
                                   (__attribute__((address_space(3))) unsigned int*)l, 16, 0, 0);
}

// scale 8 consecutive fp32 -> bf16x8 frag
__device__ __forceinline__ bf16x8 frag8(const float* p, float k) {
  float4 f0 = *(const float4*)p, f1 = *(const float4*)(p + 4);
  bf16x8 v;
  v[0] = f2b(f0.x * k); v[1] = f2b(f0.y * k); v[2] = f2b(f0.z * k); v[3] = f2b(f0.w * k);
  v[4] = f2b(f1.x * k); v[5] = f2b(f1.y * k); v[6] = f2b(f1.z * k); v[7] = f2b(f1.w * k);
  return v;
}

// ---------------- merged prep: casts + conv-weight pack ----------------
// blocks [0,8192): x->Xb; [8192,8384): w_qkv; [8384,8448): w_proj; [8448,8704): pack_wc
__global__ void prep_cast(const float* __restrict__ x, const float* __restrict__ wq,
                          const float* __restrict__ wp, const float* __restrict__ wdwc,
                          u16* __restrict__ Xb, u16* __restrict__ Wqb,
                          u16* __restrict__ Wpb, u16* __restrict__ Wc) {
  int b = blockIdx.x, tid = threadIdx.x;
  if (b < 8448) {
    const float* src; u16* dst; int i;
    if (b < 8192)      { src = x;  dst = Xb;  i = b * 256 + tid; }
    else if (b < 8384) { src = wq; dst = Wqb; i = (b - 8192) * 256 + tid; }
    else               { src = wp; dst = Wpb; i = (b - 8384) * 256 + tid; }
    const float4 v = ((const float4*)src)[i];
    uint2 o;
    o.x = (unsigned)f2b(v.x) | ((unsigned)f2b(v.y) << 16);
    o.y = (unsigned)f2b(v.z) | ((unsigned)f2b(v.w) << 16);
    ((uint2*)dst)[i] = o;
  } else {
    int o = b - 8448;                        // w_dwc[o][i][t] -> Wc[o][t][i] via LDS transpose
    __shared__ u16 lds[6912];
    for (int t = tid; t < 6912; t += 256) lds[t] = f2b(wdwc[o * 6912 + t]);
    __syncthreads();
    for (int idx = tid; idx < 6912; idx += 256) {
      int tp = idx >> 8, i = idx & 255;
      Wc[o * 6912 + idx] = lds[i * 27 + tp];
    }
  }
}

// ---------------- merged: pad_v + pool_A (both depend only on QKV) ----------------
__global__ void prep_av(const u16* __restrict__ QKV, u16* __restrict__ v5,
                        float* __restrict__ Apre) {
  int b = blockIdx.x, tid = threadIdx.x;
  if (b < 4913) {          // pad_v: V -> padded 34^3 channel-last (halo zeroed)
    int idx = b * 256 + tid;
    int c8 = idx & 31, vox = idx >> 5;
    int z = vox / 1156, r2 = vox - z * 1156, y = r2 / 34, x = r2 - y * 34;
    bf16x8 val = {0, 0, 0, 0, 0, 0, 0, 0};
    if (z >= 1 && z <= 32 && y >= 1 && y <= 32 && x >= 1 && x <= 32) {
      int n = (z - 1) * 1024 + (y - 1) * 32 + (x - 1);
      val = *(const bf16x8*)(QKV + n * 768 + 512 + c8 * 8);
    }
    *(bf16x8*)(v5 + vox * 256 + c8 * 8) = val;
  } else {                 // pool_A partials (faithful torch head-interleave)
    int b2 = b - 4913;
    int a = b2 >> 3, s = b2 & 7;
    int hp = tid >> 5, dp = tid & 31;
    int p1 = a >> 4, p2 = (a >> 2) & 3, p3 = a & 3;
    float sum = 0.f;
    for (int ui = 0; ui < 64; ++ui) {
      int u = s * 64 + ui;
      int f1 = p1 * 8 + (u >> 6);
      int f2 = p2 * 8 + ((u >> 3) & 7);
      int f3 = p3 * 8 + (u & 7);
      int vox = f1 * 1024 + f2 * 32 + f3;
      int n  = ((vox & 4095) << 3) + hp;
      int cq = ((vox >> 12) << 5) + dp;
      sum += b2f(QKV[n * 768 + cq]);
    }
    atomicAdd(&Apre[(hp * 64 + a) * 32 + dp], sum);
  }
}

// ---------------- bf16 NT-GEMM pieces: BK=64 (two 32-K panels), conflict-free LDS --------

__device__ __forceinline__ void stage64(const u16* src, int row0, int ld, int k0,
                                        short* dst, int tid) {
  int wv = tid >> 6, lane = tid & 63;
  int r15 = lane & 15, kc8 = (lane >> 4) * 8;
#pragma unroll
  for (int j = 0; j < 4; ++j) {
    int p = j & 1, g = wv * 2 + (j >> 1);
    async16(src + (row0 + g * 16 + r15) * ld + k0 + p * 32 + kc8, dst + p * 4096 + g * 512);
  }
}

__device__ __forceinline__ void mfma64(const short* As, const short* Bs, int wm, int wn,
                                       int lane, f32x4 acc[4][4]) {
  const int q = lane >> 4, c = lane & 15;
  const int fo = q * 128 + c * 8;
#pragma unroll
  for (int p = 0; p < 2; ++p) {
    bf16x8 a[4], b[4];
#pragma unroll
    for (int mt = 0; mt < 4; ++mt) a[mt] = *(const bf16x8*)&As[p * 4096 + (wm * 4 + mt) * 512 + fo];
#pragma unroll
    for (int nt = 0; nt < 4; ++nt) b[nt] = *(const bf16x8*)&Bs[p * 4096 + (wn * 4 + nt) * 512 + fo];
#pragma unroll
    for (int mt = 0; mt < 4; ++mt)
#pragma unroll
      for (int nt = 0; nt < 4; ++nt)
        acc[mt][nt] = __builtin_amdgcn_mfma_f32_16x16x32_bf16(a[mt], b[nt], acc[mt][nt], 0, 0, 0);
  }
}

// QKV = Xb @ Wq^T + b, bf16 out (32768 x 768)
__global__ __launch_bounds__(256) void gemm_qkv(const u16* __restrict__ Xb,
                                                const u16* __restrict__ Wq,
                                                const float* __restrict__ bias,
                                                u16* __restrict__ QKV) {
  const int m0 = blockIdx.x * 128, n0 = blockIdx.y * 128;
  const int tid = threadIdx.x, lane = tid & 63, wv = tid >> 6;
  const int wm = wv >> 1, wn = wv & 1, q = lane >> 4, c = lane & 15;
  __shared__ short As[8192], Bs[8192];
  f32x4 acc[4][4] = {};
  for (int kb = 0; kb < 256; kb += 64) {
    stage64(Xb, m0, 256, kb, As, tid);
    stage64(Wq, n0, 256, kb, Bs, tid);
    __syncthreads();
    mfma64(As, Bs, wm, wn, lane, acc);
    __syncthreads();
  }
#pragma unroll
  for (int nt = 0; nt < 4; ++nt) {
    int col = n0 + wn * 64 + nt * 16 + c;
    float bv = bias[col];
#pragma unroll
    for (int mt = 0; mt < 4; ++mt) {
      int row = m0 + wm * 64 + mt * 16 + q * 4;
#pragma unroll
      for (int r = 0; r < 4; ++r) QKV[(row + r) * 768 + col] = f2b(acc[mt][nt][r] + bv);
    }
  }
}

// ---------------- conv: n-split x4 for occupancy (R7 post-mortem: grid was the cap) ----
// 1024 blocks (256 m-tiles x 4 n-quarters of 64 cols), LDS 21504 B -> 4 blocks/CU,
// 16 waves/CU (was 2 blocks/8 waves).  Same stage->barrier->MFMA structure; B staging
// halves to 12KB/iter, A staging unchanged; A re-read x4 is L2-absorbed.
__global__ __launch_bounds__(256) void conv_k(const u16* __restrict__ v5,
                                              const u16* __restrict__ Wc,
                                              const float* __restrict__ bias,
                                              u16* __restrict__ Xp) {
  extern __shared__ char smem[];
  const int tid = threadIdx.x, lane = tid & 63, wv = tid >> 6;
  const int q = lane >> 4, c = lane & 15;
  const int bid = blockIdx.x;
  const int xcd = bid & 7, idx = bid >> 3;          // idx 0..127
  const int n0 = (idx & 3) * 64;                    // 4 n-quarters
  const int mt_i = xcd * 32 + (idx >> 2);           // m-tile 0..255
  const int m0 = mt_i * 128;
  const int z0 = mt_i >> 3, y0 = (mt_i & 7) * 4;
  const int wm = wv >> 1, wn = wv & 1;
  const int r15 = lane & 15, kq8 = (lane >> 4) * 8;
  short* As = (short*)smem;            // 9 groups * 512 shorts = 9216 B
  short* Bs = (short*)(smem + 9216);   // 3 dx * 4 groups * 512 = 12288 B
  f32x4 acc[4][2] = {};
  const u16* browB = Wc + (n0 + r15) * 6912 + kq8;
  for (int dzy = 0; dzy < 9; ++dzy) {
    int dz = dzy / 3, dy = dzy - dz * 3;
    int base = (z0 + dz) * 1156 + (y0 + dy) * 34;
    int tap0 = dzy * 3;
    for (int panel = 0; panel < 8; ++panel) {
      int choff = panel * 32 + kq8;
      for (int g = wv; g < 9; g += 4) {
        int row = base + g * 16 + r15;
        row = row < 39303 ? row : 39303;           // clamp tail (garbage, never read)
        async16(v5 + row * 256 + choff, As + g * 512);
      }
#pragma unroll
      for (int i = wv; i < 12; i += 4) {
        int dx = i >> 2, g = i & 3;
        async16(browB + g * (16 * 6912) + (tap0 + dx) * 256 + panel * 32, Bs + i * 512);
      }
      __syncthreads();
#pragma unroll
      for (int dx = 0; dx < 3; ++dx) {
        bf16x8 a[4], b[2];
#pragma unroll
        for (int mt = 0; mt < 4; ++mt) {
          int M = wm * 64 + mt * 16 + c;
          int vx = M + 2 * (M >> 5) + dx;
          a[mt] = *(const bf16x8*)&As[(vx >> 4) * 512 + q * 128 + (vx & 15) * 8];
        }
#pragma unroll
        for (int nt = 0; nt < 2; ++nt)
          b[nt] = *(const bf16x8*)&Bs[dx * 2048 + (wn * 2 + nt) * 512 + q * 128 + c * 8];
#pragma unroll
        for (int mt = 0; mt < 4; ++mt)
#pragma unroll
          for (int nt = 0; nt < 2; ++nt)
            acc[mt][nt] = __builtin_amdgcn_mfma_f32_16x16x32_bf16(a[mt], b[nt], acc[mt][nt], 0, 0, 0);
      }
      __syncthreads();
    }
  }
#pragma unroll
  for (int nt = 0; nt < 2; ++nt) {
    int col = n0 + wn * 32 + nt * 16 + c;
    float bv = bias[col];
#pragma unroll
    for (int mt = 0; mt < 4; ++mt) {
      int row = m0 + wm * 64 + mt * 16 + q * 4;
#pragma unroll
      for (int r = 0; r < 4; ++r) Xp[(row + r) * 256 + col] = f2b(acc[mt][nt][r] + bv);
    }
  }
}

// ---------------- s1_attn (unchanged from R7) ----------
// 1024 blocks (8 heads x 128 chunks of 256 tokens), 50688 B LDS -> 3 blocks/CU.
__global__ __launch_bounds__(256) void s1_k(const u16* __restrict__ QKV,
                                            const float* __restrict__ Apre,
                                            float* __restrict__ avac,
                                            float* __restrict__ rsum) {
  extern __shared__ char smem[];
  const int tid = threadIdx.x, lane = tid & 63, wv = tid >> 6;
  const int q = lane >> 4, c = lane & 15;
  const int vb = blockIdx.x;                 // 0..1023: h = vb>>7 in [0,8)
  const int h = vb >> 7, n0 = (vb & 127) * 256;
  u16* E  = (u16*)smem;            // [64 agents][264] bf16 (pitch-padded)
  u16* VT = (u16*)(smem + 33792);  // [32 d][264] bf16
  float* RED = (float*)smem;       // overlay after E consumed: [4 waves][2048]
  { // stage V chunk transposed: VT[d][tok_local]
    const u16* vrow = QKV + (n0 + tid) * 768 + 512 + h * 32;
#pragma unroll
    for (int d8 = 0; d8 < 4; ++d8) {
      bf16x8 v = *(const bf16x8*)(vrow + d8 * 8);
#pragma unroll
      for (int e = 0; e < 8; ++e) VT[(d8 * 8 + e) * 264 + tid] = (u16)v[e];
    }
  }
  { // QK^T (M=64 agents, N=64 tokens per wave, K=32) + exp -> E
    bf16x8 af[4], bf[4];
#pragma unroll
    for (int mt = 0; mt < 4; ++mt)
      af[mt] = frag8(Apre + h * 2048 + (mt * 16 + c) * 32 + q * 8, KSCALE);
#pragma unroll
    for (int nt = 0; nt < 4; ++nt)
      bf[nt] = *(const bf16x8*)(QKV + (n0 + wv * 64 + nt * 16 + c) * 768 + 256 + h * 32 + q * 8);
#pragma unroll
    for (int mt = 0; mt < 4; ++mt)
#pragma unroll
      for (int nt = 0; nt < 4; ++nt) {
        f32x4 s = {0.f, 0.f, 0.f, 0.f};
        s = __builtin_amdgcn_mfma_f32_16x16x32_bf16(af[mt], bf[nt], s, 0, 0, 0);
#pragma unroll
        for (int r = 0; r < 4; ++r) {
          int a = mt * 16 + q * 4 + r, nl = wv * 64 + nt * 16 + c;
          E[a * 264 + nl] = f2b(__expf(s[r]));
        }
      }
  }
  __syncthreads();
  { // row sums of E (denominator partials)
    int a = tid >> 2, seg = tid & 3;
    float sum = 0.f;
    for (int i = 0; i < 64; ++i) sum += b2f(E[a * 264 + seg * 64 + i]);
    sum += __shfl_xor(sum, 1);
    sum += __shfl_xor(sum, 2);
    if (seg == 0) atomicAdd(&rsum[h * 64 + a], sum);
  }
  // PV: each wave reduces its own 64-token K-slab (M=64 agents, N=32 d)
  f32x4 pv[4][2] = {};
#pragma unroll
  for (int ks = 0; ks < 2; ++ks) {
    bf16x8 ap[4], bp[2];
#pragma unroll
    for (int mt = 0; mt < 4; ++mt)
      ap[mt] = *(const bf16x8*)&E[(mt * 16 + c) * 264 + wv * 64 + ks * 32 + q * 8];
#pragma unroll
    for (int nt = 0; nt < 2; ++nt)
      bp[nt] = *(const bf16x8*)&VT[(nt * 16 + c) * 264 + wv * 64 + ks * 32 + q * 8];
#pragma unroll
    for (int mt = 0; mt < 4; ++mt)
#pragma unroll
      for (int nt = 0; nt < 2; ++nt)
        pv[mt][nt] = __builtin_amdgcn_mfma_f32_16x16x32_bf16(ap[mt], bp[nt], pv[mt][nt], 0, 0, 0);
  }
  __syncthreads();            // all E/VT reads done; reuse smem as RED
#pragma unroll
  for (int mt = 0; mt < 4; ++mt)
#pragma unroll
    for (int nt = 0; nt < 2; ++nt)
#pragma unroll
      for (int r = 0; r < 4; ++r)
        RED[wv * 2048 + (mt * 16 + q * 4 + r) * 32 + nt * 16 + c] = pv[mt][nt][r];
  __syncthreads();
  for (int idx = tid; idx < 2048; idx += 256) {
    float t = RED[idx] + RED[2048 + idx] + RED[4096 + idx] + RED[6144 + idx];
    atomicAdd(&avac[h * 2048 + idx], t);
  }
}

// out = Xp @ Wp^T + b_proj, fp32 out (32768 x 256)
__global__ __launch_bounds__(256) void gemm_proj(const u16* __restrict__ Xp,
                                                 const u16* __restrict__ Wp,
                                                 const float* __restrict__ bias,
                                                 float* __restrict__ out) {
  const int m0 = blockIdx.x * 128, n0 = blockIdx.y * 128;
  const int tid = threadIdx.x, lane = tid & 63, wv = tid >> 6;
  const int wm = wv >> 1, wn = wv & 1, q = lane >> 4, c = lane & 15;
  __shared__ short As[8192], Bs[8192];
  f32x4 acc[4][4] = {};
  for (int kb = 0; kb < 256; kb += 64) {
    stage64(Xp, m0, 256, kb, As, tid);
    stage64(Wp, n0, 256, kb, Bs, tid);
    __syncthreads();
    mfma64(As, Bs, wm, wn, lane, acc);
    __syncthreads();
  }
#pragma unroll
  for (int nt = 0; nt < 4; ++nt) {
    int col = n0 + wn * 64 + nt * 16 + c;
    float bv = bias[col];
#pragma unroll
    for (int mt = 0; mt < 4; ++mt) {
      int row = m0 + wm * 64 + mt * 16 + q * 4;
#pragma unroll
      for (int r = 0; r < 4; ++r) out[(row + r) * 256 + col] = acc[mt][nt][r] + bv;
    }
  }
}

// ---------------- stage-2: queries attend agents; normalize agent_v in-preamble ----------
__global__ __launch_bounds__(256) void s2_attn(const u16* __restrict__ QKV,
                                               const float* __restrict__ Apre,
                                               const float* __restrict__ avac,
                                               const float* __restrict__ rsum,
                                               u16* __restrict__ Xp) {
  const int h = blockIdx.y, n0 = blockIdx.x * 256;
  const int tid = threadIdx.x, lane = tid & 63, wv = tid >> 6;
  const int q = lane >> 4, c = lane & 15;
  extern __shared__ char smem[];
  u16* P = (u16*)smem;                  // [256 tok][72] bf16 (36864 B)
  float* O = (float*)smem;              // overlay later: [32 d][258] f32 (33024 B)
  u16* AVT = (u16*)(smem + 36864);      // [32 d][72 pitch] bf16 normalized agent_v

  // fold s1_norm: normalize+transpose agent_v for this head into LDS
  for (int j = 0; j < 8; ++j) {
    int i = j * 256 + tid;              // i = a*32 + d
    int a = i >> 5, d = i & 31;
    AVT[d * 72 + a] = f2b(avac[h * 2048 + i] / rsum[h * 64 + a]);
  }

  f32x4 s[4][4];
  { // QK^T: M=64 tokens/wave, N=64 agents, K=32
    bf16x8 af[4], bf[4];
#pragma unroll
    for (int mt = 0; mt < 4; ++mt)
      af[mt] = *(const bf16x8*)(QKV + (n0 + wv * 64 + mt * 16 + c) * 768 + h * 32 + q * 8);
#pragma unroll
    for (int nt = 0; nt < 4; ++nt)
      bf[nt] = frag8(Apre + h * 2048 + (nt * 16 + c) * 32 + q * 8, KSCALE);
#pragma unroll
    for (int mt = 0; mt < 4; ++mt)
#pragma unroll
      for (int nt = 0; nt < 4; ++nt) {
        f32x4 z = {0.f, 0.f, 0.f, 0.f};
        s[mt][nt] = __builtin_amdgcn_mfma_f32_16x16x32_bf16(af[mt], bf[nt], z, 0, 0, 0);
      }
  }
  // softmax across 64 agents per token row: 4 reg-values + shfl over 16-lane col group
#pragma unroll
  for (int mt = 0; mt < 4; ++mt)
#pragma unroll
    for (int r = 0; r < 4; ++r) {
      float v0 = s[mt][0][r], v1 = s[mt][1][r], v2 = s[mt][2][r], v3 = s[mt][3][r];
      float mx = fmaxf(fmaxf(v0, v1), fmaxf(v2, v3));
      mx = fmaxf(mx, __shfl_xor(mx, 1));
      mx = fmaxf(mx, __shfl_xor(mx, 2));
      mx = fmaxf(mx, __shfl_xor(mx, 4));
      mx = fmaxf(mx, __shfl_xor(mx, 8));
      float e0 = __expf(v0 - mx), e1 = __expf(v1 - mx), e2 = __expf(v2 - mx), e3 = __expf(v3 - mx);
      float sm = e0 + e1 + e2 + e3;
      sm += __shfl_xor(sm, 1);
      sm += __shfl_xor(sm, 2);
      sm += __shfl_xor(sm, 4);
      sm += __shfl_xor(sm, 8);
      float inv = 1.0f / sm;
      int tok = wv * 64 + mt * 16 + q * 4 + r;
      P[tok * 72 +      c] = f2b(e0 * inv);
      P[tok * 72 + 16 + c] = f2b(e1 * inv);
      P[tok * 72 + 32 + c] = f2b(e2 * inv);
      P[tok * 72 + 48 + c] = f2b(e3 * inv);
    }
  __syncthreads();   // also fences the AVT preamble writes
  // PV: O = P(64x64) @ agent_v(64x32); AVT is [d][a] in LDS (K=a contiguous)
  f32x4 o[4][2] = {};
#pragma unroll
  for (int ks = 0; ks < 2; ++ks) {
    bf16x8 ap[4], bv[2];
#pragma unroll
    for (int mt = 0; mt < 4; ++mt)
      ap[mt] = *(const bf16x8*)&P[(wv * 64 + mt * 16 + c) * 72 + ks * 32 + q * 8];
#pragma unroll
    for (int nt = 0; nt < 2; ++nt)
      bv[nt] = *(const bf16x8*)&AVT[(nt * 16 + c) * 72 + ks * 32 + q * 8];
#pragma unroll
    for (int mt = 0; mt < 4; ++mt)
#pragma unroll
      for (int nt = 0; nt < 2; ++nt)
        o[mt][nt] = __builtin_amdgcn_mfma_f32_16x16x32_bf16(ap[mt], bv[nt], o[mt][nt], 0, 0, 0);
  }
  __syncthreads();  // P reads done; reuse smem as O
#pragma unroll
  for (int mt = 0; mt < 4; ++mt)
#pragma unroll
    for (int nt = 0; nt < 2; ++nt)
#pragma unroll
      for (int r = 0; r < 4; ++r)
        O[(nt * 16 + c) * 258 + wv * 64 + mt * 16 + q * 4 + r] = o[mt][nt][r];
  __syncthreads();
  // coalesced RMW: flat offset (h*32+d)*32768 + n == row-major (n',c') of the torch reshape
  for (int d = 0; d < 32; ++d) {
    int addr = (h * 32 + d) * 32768 + n0 + tid;
    Xp[addr] = f2b(b2f(Xp[addr]) + O[d * 258 + tid]);
  }
}

// ---------------- launch ----------------

extern "C" void kernel_launch(void* const* d_in, const int* in_sizes, int n_in,
                              void* d_out, int out_size, void* d_ws, size_t ws_size,
                              hipStream_t stream) {
  const float* x      = (const float*)d_in[0];
  const float* w_qkv  = (const float*)d_in[1];
  const float* b_qkv  = (const float*)d_in[2];
  const float* w_proj = (const float*)d_in[3];
  const float* b_proj = (const float*)d_in[4];
  const float* w_dwc  = (const float*)d_in[5];
  const float* b_dwc  = (const float*)d_in[6];
  float* out = (float*)d_out;
  char* ws = (char*)d_ws;

  u16* Xb   = (u16*)(ws);              // 16 MB; conv writes Xp here (x-cast dead by then)
  u16* QKV  = (u16*)(ws + 16777216);   // 48 MB bf16 (32768 x 768)
  u16* V5   = (u16*)(ws + 67108864);   // 20.1 MB padded volume
  u16* Wc   = (u16*)(ws + 87232512);   // 3.5 MB conv weights [o][t][i]
  u16* Wqb  = (u16*)(ws + 90771456);
  u16* Wpb  = (u16*)(ws + 91164672);
  float* AVAC = (float*)(ws + 91361280);   // 64 KB
  float* RSUM = (float*)(ws + 91426816);   // 2 KB
  float* APRE = (float*)(ws + 91428864);   // 64 KB
  u16* Xp = Xb;

  hipMemsetAsync(AVAC, 0, 65536 + 2048 + 65536, stream);  // AVAC+RSUM+APRE contiguous
  prep_cast<<<8704, 256, 0, stream>>>(x, w_qkv, w_proj, w_dwc, Xb, Wqb, Wpb, Wc);
  gemm_qkv<<<dim3(256, 6), 256, 0, stream>>>(Xb, Wqb, b_qkv, QKV);
  prep_av<<<5425, 256, 0, stream>>>(QKV, V5, APRE);
  conv_k<<<1024, 256, 21504, stream>>>(V5, Wc, b_dwc, Xp);
  s1_k<<<1024, 256, 50688, stream>>>(QKV, APRE, AVAC, RSUM);
  s2_attn<<<dim3(128, 8), 256, 41472, stream>>>(QKV, APRE, AVAC, RSUM, Xp);
  gemm_proj<<<dim3(256, 2), 256, 0, stream>>>(Xp, Wpb, b_proj, out);
}

// Round 9
// 363.974 us; speedup vs baseline: 1.0821x; 1.0821x over previous
//
#include <hip/hip_runtime.h>
#include <stdint.h>

typedef unsigned short u16;
typedef __attribute__((ext_vector_type(8))) short bf16x8;   // 8 bf16 = 4 VGPRs (MFMA A/B frag)
typedef __attribute__((ext_vector_type(4))) float f32x4;    // MFMA C/D frag

#define KSCALE (0.17677669529663687f / 512.0f)

__device__ __forceinline__ u16 f2b(float f) {
  unsigned u = __float_as_uint(f);
  unsigned r = (u + 0x7fffu + ((u >> 16) & 1u)) >> 16;  // RNE
  return (u16)r;
}
__device__ __forceinline__ float b2f(u16 s) { return __uint_as_float(((unsigned)s) << 16); }

// async global->LDS, 16B per lane; LDS dest = wave-uniform base + lane*16
__device__ __forceinline__ void async16(const void* g, void* l) {
  __builtin_amdgcn_global_load_lds((const __attribute__((address_space(1))) unsigned int*)g,
                                   (__attribute__((address_space(3))) unsigned int*)l, 16, 0, 0);
}

// scale 8 consecutive fp32 -> bf16x8 frag
__device__ __forceinline__ bf16x8 frag8(const float* p, float k) {
  float4 f0 = *(const float4*)p, f1 = *(const float4*)(p + 4);
  bf16x8 v;
  v[0] = f2b(f0.x * k); v[1] = f2b(f0.y * k); v[2] = f2b(f0.z * k); v[3] = f2b(f0.w * k);
  v[4] = f2b(f1.x * k); v[5] = f2b(f1.y * k); v[6] = f2b(f1.z * k); v[7] = f2b(f1.w * k);
  return v;
}

// ---------------- merged prep: casts + conv-weight pack ----------------
// blocks [0,8192): x->Xb; [8192,8384): w_qkv; [8384,8448): w_proj; [8448,8704): pack_wc
__global__ void prep_cast(const float* __restrict__ x, const float* __restrict__ wq,
                          const float* __restrict__ wp, const float* __restrict__ wdwc,
                          u16* __restrict__ Xb, u16* __restrict__ Wqb,
                          u16* __restrict__ Wpb, u16* __restrict__ Wc) {
  int b = blockIdx.x, tid = threadIdx.x;
  if (b < 8448) {
    const float* src; u16* dst; int i;
    if (b < 8192)      { src = x;  dst = Xb;  i = b * 256 + tid; }
    else if (b < 8384) { src = wq; dst = Wqb; i = (b - 8192) * 256 + tid; }
    else               { src = wp; dst = Wpb; i = (b - 8384) * 256 + tid; }
    const float4 v = ((const float4*)src)[i];
    uint2 o;
    o.x = (unsigned)f2b(v.x) | ((unsigned)f2b(v.y) << 16);
    o.y = (unsigned)f2b(v.z) | ((unsigned)f2b(v.w) << 16);
    ((uint2*)dst)[i] = o;
  } else {
    int o = b - 8448;                        // w_dwc[o][i][t] -> Wc[o][t][i] via LDS transpose
    __shared__ u16 lds[6912];
    for (int t = tid; t < 6912; t += 256) lds[t] = f2b(wdwc[o * 6912 + t]);
    __syncthreads();
    for (int idx = tid; idx < 6912; idx += 256) {
      int tp = idx >> 8, i = idx & 255;
      Wc[o * 6912 + idx] = lds[i * 27 + tp];
    }
  }
}

// ---------------- merged: pad_v + pool_A (both depend only on QKV) ----------------
__global__ void prep_av(const u16* __restrict__ QKV, u16* __restrict__ v5,
                        float* __restrict__ Apre) {
  int b = blockIdx.x, tid = threadIdx.x;
  if (b < 4913) {          // pad_v: V -> padded 34^3 channel-last (halo zeroed)
    int idx = b * 256 + tid;
    int c8 = idx & 31, vox = idx >> 5;
    int z = vox / 1156, r2 = vox - z * 1156, y = r2 / 34, x = r2 - y * 34;
    bf16x8 val = {0, 0, 0, 0, 0, 0, 0, 0};
    if (z >= 1 && z <= 32 && y >= 1 && y <= 32 && x >= 1 && x <= 32) {
      int n = (z - 1) * 1024 + (y - 1) * 32 + (x - 1);
      val = *(const bf16x8*)(QKV + n * 768 + 512 + c8 * 8);
    }
    *(bf16x8*)(v5 + vox * 256 + c8 * 8) = val;
  } else {                 // pool_A partials (faithful torch head-interleave)
    int b2 = b - 4913;
    int a = b2 >> 3, s = b2 & 7;
    int hp = tid >> 5, dp = tid & 31;
    int p1 = a >> 4, p2 = (a >> 2) & 3, p3 = a & 3;
    float sum = 0.f;
    for (int ui = 0; ui < 64; ++ui) {
      int u = s * 64 + ui;
      int f1 = p1 * 8 + (u >> 6);
      int f2 = p2 * 8 + ((u >> 3) & 7);
      int f3 = p3 * 8 + (u & 7);
      int vox = f1 * 1024 + f2 * 32 + f3;
      int n  = ((vox & 4095) << 3) + hp;
      int cq = ((vox >> 12) << 5) + dp;
      sum += b2f(QKV[n * 768 + cq]);
    }
    atomicAdd(&Apre[(hp * 64 + a) * 32 + dp], sum);
  }
}

// ---------------- bf16 NT-GEMM pieces: BK=64 (two 32-K panels), conflict-free LDS --------

__device__ __forceinline__ void stage64(const u16* src, int row0, int ld, int k0,
                                        short* dst, int tid) {
  int wv = tid >> 6, lane = tid & 63;
  int r15 = lane & 15, kc8 = (lane >> 4) * 8;
#pragma unroll
  for (int j = 0; j < 4; ++j) {
    int p = j & 1, g = wv * 2 + (j >> 1);
    async16(src + (row0 + g * 16 + r15) * ld + k0 + p * 32 + kc8, dst + p * 4096 + g * 512);
  }
}

__device__ __forceinline__ void mfma64(const short* As, const short* Bs, int wm, int wn,
                                       int lane, f32x4 acc[4][4]) {
  const int q = lane >> 4, c = lane & 15;
  const int fo = q * 128 + c * 8;
#pragma unroll
  for (int p = 0; p < 2; ++p) {
    bf16x8 a[4], b[4];
#pragma unroll
    for (int mt = 0; mt < 4; ++mt) a[mt] = *(const bf16x8*)&As[p * 4096 + (wm * 4 + mt) * 512 + fo];
#pragma unroll
    for (int nt = 0; nt < 4; ++nt) b[nt] = *(const bf16x8*)&Bs[p * 4096 + (wn * 4 + nt) * 512 + fo];
#pragma unroll
    for (int mt = 0; mt < 4; ++mt)
#pragma unroll
      for (int nt = 0; nt < 4; ++nt)
        acc[mt][nt] = __builtin_amdgcn_mfma_f32_16x16x32_bf16(a[mt], b[nt], acc[mt][nt], 0, 0, 0);
  }
}

// QKV = Xb @ Wq^T + b, bf16 out (32768 x 768)
__global__ __launch_bounds__(256) void gemm_qkv(const u16* __restrict__ Xb,
                                                const u16* __restrict__ Wq,
                                                const float* __restrict__ bias,
                                                u16* __restrict__ QKV) {
  const int m0 = blockIdx.x * 128, n0 = blockIdx.y * 128;
  const int tid = threadIdx.x, lane = tid & 63, wv = tid >> 6;
  const int wm = wv >> 1, wn = wv & 1, q = lane >> 4, c = lane & 15;
  __shared__ short As[8192], Bs[8192];
  f32x4 acc[4][4] = {};
  for (int kb = 0; kb < 256; kb += 64) {
    stage64(Xb, m0, 256, kb, As, tid);
    stage64(Wq, n0, 256, kb, Bs, tid);
    __syncthreads();
    mfma64(As, Bs, wm, wn, lane, acc);
    __syncthreads();
  }
#pragma unroll
  for (int nt = 0; nt < 4; ++nt) {
    int col = n0 + wn * 64 + nt * 16 + c;
    float bv = bias[col];
#pragma unroll
    for (int mt = 0; mt < 4; ++mt) {
      int row = m0 + wm * 64 + mt * 16 + q * 4;
#pragma unroll
      for (int r = 0; r < 4; ++r) QKV[(row + r) * 768 + col] = f2b(acc[mt][nt][r] + bv);
    }
  }
}

// ---------------- conv: B-reuse via 2 m-tiles per block (R8 post-mortem: bytes-bound) ----
// Time tracked staged bytes across R7/R8 (1.18GB->159us, 1.53GB->212us).  B (weights) was
// 74% of staged bytes, re-staged by every m-tile.  Now: 256 blocks x 512 threads; each
// block = 2 adjacent m-tiles (256 rows, contiguous y, same z0) x 128 cols.  Per
// (dzy,panel): ONE 18-group A slab (288 rows, both tiles' halos) + the same 24-group B
// serving 2x the MFMA.  Staged total 774 MB = 0.66x R7.  Per-wave acc stays [4][4].
__global__ __launch_bounds__(512) void conv_k(const u16* __restrict__ v5,
                                              const u16* __restrict__ Wc,
                                              const float* __restrict__ bias,
                                              u16* __restrict__ Xp) {
  extern __shared__ char smem[];
  const int tid = threadIdx.x, lane = tid & 63, wv = tid >> 6;   // 8 waves
  const int q = lane >> 4, c = lane & 15;
  const int bid = blockIdx.x;
  const int xcd = bid & 7, idx = bid >> 3;        // idx 0..31
  const int n0 = (idx & 1) * 128;
  const int pair = xcd * 16 + (idx >> 1);         // 0..127 (2 m-tiles each)
  const int z0 = pair >> 2, y0 = (pair & 3) * 8;  // 8 output y-rows
  const int tile = wv >> 2, wm = (wv >> 1) & 1, wn = wv & 1;
  const int r15 = lane & 15, kq8 = (lane >> 4) * 8;
  short* As = (short*)smem;             // 18 groups * 512 shorts = 18432 B (288 rows)
  short* Bs = (short*)(smem + 18432);   // 24 groups * 512 = 24576 B
  f32x4 acc[4][4] = {};
  const u16* browB = Wc + (n0 + r15) * 6912 + kq8;
  for (int dzy = 0; dzy < 9; ++dzy) {
    int dz = dzy / 3, dy = dzy - dz * 3;
    int base = (z0 + dz) * 1156 + (y0 + dy) * 34;
    int tap0 = dzy * 3;
    for (int panel = 0; panel < 8; ++panel) {
      int choff = panel * 32 + kq8;
      for (int g = wv; g < 18; g += 8) {
        int row = base + g * 16 + r15;
        row = row < 39303 ? row : 39303;           // clamp tail (garbage, never read)
        async16(v5 + row * 256 + choff, As + g * 512);
      }
#pragma unroll
      for (int i = wv; i < 24; i += 8) {
        int dx = i >> 3, g = i & 7;
        async16(browB + g * (16 * 6912) + (tap0 + dx) * 256 + panel * 32, Bs + i * 512);
      }
      __syncthreads();
#pragma unroll
      for (int dx = 0; dx < 3; ++dx) {
        bf16x8 a[4], b[4];
#pragma unroll
        for (int mt = 0; mt < 4; ++mt) {
          int M = wm * 64 + mt * 16 + c;
          int vx = tile * 136 + M + 2 * (M >> 5) + dx;   // tile2 offset = 4 y-lines = 136 rows
          a[mt] = *(const bf16x8*)&As[(vx >> 4) * 512 + q * 128 + (vx & 15) * 8];
        }
#pragma unroll
        for (int nt = 0; nt < 4; ++nt)
          b[nt] = *(const bf16x8*)&Bs[dx * 4096 + (wn * 4 + nt) * 512 + q * 128 + c * 8];
#pragma unroll
        for (int mt = 0; mt < 4; ++mt)
#pragma unroll
          for (int nt = 0; nt < 4; ++nt)
            acc[mt][nt] = __builtin_amdgcn_mfma_f32_16x16x32_bf16(a[mt], b[nt], acc[mt][nt], 0, 0, 0);
      }
      __syncthreads();
    }
  }
#pragma unroll
  for (int nt = 0; nt < 4; ++nt) {
    int col = n0 + wn * 64 + nt * 16 + c;
    float bv = bias[col];
#pragma unroll
    for (int mt = 0; mt < 4; ++mt) {
      int row = pair * 256 + tile * 128 + wm * 64 + mt * 16 + q * 4;
#pragma unroll
      for (int r = 0; r < 4; ++r) Xp[(row + r) * 256 + col] = f2b(acc[mt][nt][r] + bv);
    }
  }
}

// ---------------- s1_attn (unchanged) ----------
// 1024 blocks (8 heads x 128 chunks of 256 tokens), 50688 B LDS -> 3 blocks/CU.
__global__ __launch_bounds__(256) void s1_k(const u16* __restrict__ QKV,
                                            const float* __restrict__ Apre,
                                            float* __restrict__ avac,
                                            float* __restrict__ rsum) {
  extern __shared__ char smem[];
  const int tid = threadIdx.x, lane = tid & 63, wv = tid >> 6;
  const int q = lane >> 4, c = lane & 15;
  const int vb = blockIdx.x;                 // 0..1023: h = vb>>7 in [0,8)
  const int h = vb >> 7, n0 = (vb & 127) * 256;
  u16* E  = (u16*)smem;            // [64 agents][264] bf16 (pitch-padded)
  u16* VT = (u16*)(smem + 33792);  // [32 d][264] bf16
  float* RED = (float*)smem;       // overlay after E consumed: [4 waves][2048]
  { // stage V chunk transposed: VT[d][tok_local]
    const u16* vrow = QKV + (n0 + tid) * 768 + 512 + h * 32;
#pragma unroll
    for (int d8 = 0; d8 < 4; ++d8) {
      bf16x8 v = *(const bf16x8*)(vrow + d8 * 8);
#pragma unroll
      for (int e = 0; e < 8; ++e) VT[(d8 * 8 + e) * 264 + tid] = (u16)v[e];
    }
  }
  { // QK^T (M=64 agents, N=64 tokens per wave, K=32) + exp -> E
    bf16x8 af[4], bf[4];
#pragma unroll
    for (int mt = 0; mt < 4; ++mt)
      af[mt] = frag8(Apre + h * 2048 + (mt * 16 + c) * 32 + q * 8, KSCALE);
#pragma unroll
    for (int nt = 0; nt < 4; ++nt)
      bf[nt] = *(const bf16x8*)(QKV + (n0 + wv * 64 + nt * 16 + c) * 768 + 256 + h * 32 + q * 8);
#pragma unroll
    for (int mt = 0; mt < 4; ++mt)
#pragma unroll
      for (int nt = 0; nt < 4; ++nt) {
        f32x4 s = {0.f, 0.f, 0.f, 0.f};
        s = __builtin_amdgcn_mfma_f32_16x16x32_bf16(af[mt], bf[nt], s, 0, 0, 0);
#pragma unroll
        for (int r = 0; r < 4; ++r) {
          int a = mt * 16 + q * 4 + r, nl = wv * 64 + nt * 16 + c;
          E[a * 264 + nl] = f2b(__expf(s[r]));
        }
      }
  }
  __syncthreads();
  { // row sums of E (denominator partials)
    int a = tid >> 2, seg = tid & 3;
    float sum = 0.f;
    for (int i = 0; i < 64; ++i) sum += b2f(E[a * 264 + seg * 64 + i]);
    sum += __shfl_xor(sum, 1);
    sum += __shfl_xor(sum, 2);
    if (seg == 0) atomicAdd(&rsum[h * 64 + a], sum);
  }
  // PV: each wave reduces its own 64-token K-slab (M=64 agents, N=32 d)
  f32x4 pv[4][2] = {};
#pragma unroll
  for (int ks = 0; ks < 2; ++ks) {
    bf16x8 ap[4], bp[2];
#pragma unroll
    for (int mt = 0; mt < 4; ++mt)
      ap[mt] = *(const bf16x8*)&E[(mt * 16 + c) * 264 + wv * 64 + ks * 32 + q * 8];
#pragma unroll
    for (int nt = 0; nt < 2; ++nt)
      bp[nt] = *(const bf16x8*)&VT[(nt * 16 + c) * 264 + wv * 64 + ks * 32 + q * 8];
#pragma unroll
    for (int mt = 0; mt < 4; ++mt)
#pragma unroll
      for (int nt = 0; nt < 2; ++nt)
        pv[mt][nt] = __builtin_amdgcn_mfma_f32_16x16x32_bf16(ap[mt], bp[nt], pv[mt][nt], 0, 0, 0);
  }
  __syncthreads();            // all E/VT reads done; reuse smem as RED
#pragma unroll
  for (int mt = 0; mt < 4; ++mt)
#pragma unroll
    for (int nt = 0; nt < 2; ++nt)
#pragma unroll
      for (int r = 0; r < 4; ++r)
        RED[wv * 2048 + (mt * 16 + q * 4 + r) * 32 + nt * 16 + c] = pv[mt][nt][r];
  __syncthreads();
  for (int idx = tid; idx < 2048; idx += 256) {
    float t = RED[idx] + RED[2048 + idx] + RED[4096 + idx] + RED[6144 + idx];
    atomicAdd(&avac[h * 2048 + idx], t);
  }
}

// out = Xp @ Wp^T + b_proj, fp32 out (32768 x 256)
__global__ __launch_bounds__(256) void gemm_proj(const u16* __restrict__ Xp,
                                                 const u16* __restrict__ Wp,
                                                 const float* __restrict__ bias,
                                                 float* __restrict__ out) {
  const int m0 = blockIdx.x * 128, n0 = blockIdx.y * 128;
  const int tid = threadIdx.x, lane = tid & 63, wv = tid >> 6;
  const int wm = wv >> 1, wn = wv & 1, q = lane >> 4, c = lane & 15;
  __shared__ short As[8192], Bs[8192];
  f32x4 acc[4][4] = {};
  for (int kb = 0; kb < 256; kb += 64) {
    stage64(Xp, m0, 256, kb, As, tid);
    stage64(Wp, n0, 256, kb, Bs, tid);
    __syncthreads();
    mfma64(As, Bs, wm, wn, lane, acc);
    __syncthreads();
  }
#pragma unroll
  for (int nt = 0; nt < 4; ++nt) {
    int col = n0 + wn * 64 + nt * 16 + c;
    float bv = bias[col];
#pragma unroll
    for (int mt = 0; mt < 4; ++mt) {
      int row = m0 + wm * 64 + mt * 16 + q * 4;
#pragma unroll
      for (int r = 0; r < 4; ++r) out[(row + r) * 256 + col] = acc[mt][nt][r] + bv;
    }
  }
}

// ---------------- stage-2: queries attend agents; normalize agent_v in-preamble ----------
__global__ __launch_bounds__(256) void s2_attn(const u16* __restrict__ QKV,
                                               const float* __restrict__ Apre,
                                               const float* __restrict__ avac,
                                               const float* __restrict__ rsum,
                                               u16* __restrict__ Xp) {
  const int h = blockIdx.y, n0 = blockIdx.x * 256;
  const int tid = threadIdx.x, lane = tid & 63, wv = tid >> 6;
  const int q = lane >> 4, c = lane & 15;
  extern __shared__ char smem[];
  u16* P = (u16*)smem;                  // [256 tok][72] bf16 (36864 B)
  float* O = (float*)smem;              // overlay later: [32 d][258] f32 (33024 B)
  u16* AVT = (u16*)(smem + 36864);      // [32 d][72 pitch] bf16 normalized agent_v

  // fold s1_norm: normalize+transpose agent_v for this head into LDS
  for (int j = 0; j < 8; ++j) {
    int i = j * 256 + tid;              // i = a*32 + d
    int a = i >> 5, d = i & 31;
    AVT[d * 72 + a] = f2b(avac[h * 2048 + i] / rsum[h * 64 + a]);
  }

  f32x4 s[4][4];
  { // QK^T: M=64 tokens/wave, N=64 agents, K=32
    bf16x8 af[4], bf[4];
#pragma unroll
    for (int mt = 0; mt < 4; ++mt)
      af[mt] = *(const bf16x8*)(QKV + (n0 + wv * 64 + mt * 16 + c) * 768 + h * 32 + q * 8);
#pragma unroll
    for (int nt = 0; nt < 4; ++nt)
      bf[nt] = frag8(Apre + h * 2048 + (nt * 16 + c) * 32 + q * 8, KSCALE);
#pragma unroll
    for (int mt = 0; mt < 4; ++mt)
#pragma unroll
      for (int nt = 0; nt < 4; ++nt) {
        f32x4 z = {0.f, 0.f, 0.f, 0.f};
        s[mt][nt] = __builtin_amdgcn_mfma_f32_16x16x32_bf16(af[mt], bf[nt], z, 0, 0, 0);
      }
  }
  // softmax across 64 agents per token row: 4 reg-values + shfl over 16-lane col group
#pragma unroll
  for (int mt = 0; mt < 4; ++mt)
#pragma unroll
    for (int r = 0; r < 4; ++r) {
      float v0 = s[mt][0][r], v1 = s[mt][1][r], v2 = s[mt][2][r], v3 = s[mt][3][r];
      float mx = fmaxf(fmaxf(v0, v1), fmaxf(v2, v3));
      mx = fmaxf(mx, __shfl_xor(mx, 1));
      mx = fmaxf(mx, __shfl_xor(mx, 2));
      mx = fmaxf(mx, __shfl_xor(mx, 4));
      mx = fmaxf(mx, __shfl_xor(mx, 8));
      float e0 = __expf(v0 - mx), e1 = __expf(v1 - mx), e2 = __expf(v2 - mx), e3 = __expf(v3 - mx);
      float sm = e0 + e1 + e2 + e3;
      sm += __shfl_xor(sm, 1);
      sm += __shfl_xor(sm, 2);
      sm += __shfl_xor(sm, 4);
      sm += __shfl_xor(sm, 8);
      float inv = 1.0f / sm;
      int tok = wv * 64 + mt * 16 + q * 4 + r;
      P[tok * 72 +      c] = f2b(e0 * inv);
      P[tok * 72 + 16 + c] = f2b(e1 * inv);
      P[tok * 72 + 32 + c] = f2b(e2 * inv);
      P[tok * 72 + 48 + c] = f2b(e3 * inv);
    }
  __syncthreads();   // also fences the AVT preamble writes
  // PV: O = P(64x64) @ agent_v(64x32); AVT is [d][a] in LDS (K=a contiguous)
  f32x4 o[4][2] = {};
#pragma unroll
  for (int ks = 0; ks < 2; ++ks) {
    bf16x8 ap[4], bv[2];
#pragma unroll
    for (int mt = 0; mt < 4; ++mt)
      ap[mt] = *(const bf16x8*)&P[(wv * 64 + mt * 16 + c) * 72 + ks * 32 + q * 8];
#pragma unroll
    for (int nt = 0; nt < 2; ++nt)
      bv[nt] = *(const bf16x8*)&AVT[(nt * 16 + c) * 72 + ks * 32 + q * 8];
#pragma unroll
    for (int mt = 0; mt < 4; ++mt)
#pragma unroll
      for (int nt = 0; nt < 2; ++nt)
        o[mt][nt] = __builtin_amdgcn_mfma_f32_16x16x32_bf16(ap[mt], bv[nt], o[mt][nt], 0, 0, 0);
  }
  __syncthreads();  // P reads done; reuse smem as O
#pragma unroll
  for (int mt = 0; mt < 4; ++mt)
#pragma unroll
    for (int nt = 0; nt < 2; ++nt)
#pragma unroll
      for (int r = 0; r < 4; ++r)
        O[(nt * 16 + c) * 258 + wv * 64 + mt * 16 + q * 4 + r] = o[mt][nt][r];
  __syncthreads();
  // coalesced RMW: flat offset (h*32+d)*32768 + n == row-major (n',c') of the torch reshape
  for (int d = 0; d < 32; ++d) {
    int addr = (h * 32 + d) * 32768 + n0 + tid;
    Xp[addr] = f2b(b2f(Xp[addr]) + O[d * 258 + tid]);
  }
}

// ---------------- launch ----------------

extern "C" void kernel_launch(void* const* d_in, const int* in_sizes, int n_in,
                              void* d_out, int out_size, void* d_ws, size_t ws_size,
                              hipStream_t stream) {
  const float* x      = (const float*)d_in[0];
  const float* w_qkv  = (const float*)d_in[1];
  const float* b_qkv  = (const float*)d_in[2];
  const float* w_proj = (const float*)d_in[3];
  const float* b_proj = (const float*)d_in[4];
  const float* w_dwc  = (const float*)d_in[5];
  const float* b_dwc  = (const float*)d_in[6];
  float* out = (float*)d_out;
  char* ws = (char*)d_ws;

  u16* Xb   = (u16*)(ws);              // 16 MB; conv writes Xp here (x-cast dead by then)
  u16* QKV  = (u16*)(ws + 16777216);   // 48 MB bf16 (32768 x 768)
  u16* V5   = (u16*)(ws + 67108864);   // 20.1 MB padded volume
  u16* Wc   = (u16*)(ws + 87232512);   // 3.5 MB conv weights [o][t][i]
  u16* Wqb  = (u16*)(ws + 90771456);
  u16* Wpb  = (u16*)(ws + 91164672);
  float* AVAC = (float*)(ws + 91361280);   // 64 KB
  float* RSUM = (float*)(ws + 91426816);   // 2 KB
  float* APRE = (float*)(ws + 91428864);   // 64 KB
  u16* Xp = Xb;

  hipMemsetAsync(AVAC, 0, 65536 + 2048 + 65536, stream);  // AVAC+RSUM+APRE contiguous
  prep_cast<<<8704, 256, 0, stream>>>(x, w_qkv, w_proj, w_dwc, Xb, Wqb, Wpb, Wc);
  gemm_qkv<<<dim3(256, 6), 256, 0, stream>>>(Xb, Wqb, b_qkv, QKV);
  prep_av<<<5425, 256, 0, stream>>>(QKV, V5, APRE);
  conv_k<<<256, 512, 43008, stream>>>(V5, Wc, b_dwc, Xp);
  s1_k<<<1024, 256, 50688, stream>>>(QKV, APRE, AVAC, RSUM);
  s2_attn<<<dim3(128, 8), 256, 41472, stream>>>(QKV, APRE, AVAC, RSUM, Xp);
  gemm_proj<<<dim3(256, 2), 256, 0, stream>>>(Xp, Wpb, b_proj, out);
}

// Round 10
// 309.810 us; speedup vs baseline: 1.2713x; 1.1748x over previous
//
#include <hip/hip_runtime.h>
#include <stdint.h>

typedef unsigned short u16;
typedef __attribute__((ext_vector_type(8))) short bf16x8;   // 8 bf16 = 4 VGPRs (MFMA A/B frag)
typedef __attribute__((ext_vector_type(4))) float f32x4;    // MFMA C/D frag

#define KSCALE (0.17677669529663687f / 512.0f)

__device__ __forceinline__ u16 f2b(float f) {
  unsigned u = __float_as_uint(f);
  unsigned r = (u + 0x7fffu + ((u >> 16) & 1u)) >> 16;  // RNE
  return (u16)r;
}
__device__ __forceinline__ float b2f(u16 s) { return __uint_as_float(((unsigned)s) << 16); }

// async global->LDS, 16B per lane; LDS dest = wave-uniform base + lane*16
__device__ __forceinline__ void async16(const void* g, void* l) {
  __builtin_amdgcn_global_load_lds((const __attribute__((address_space(1))) unsigned int*)g,
                                   (__attribute__((address_space(3))) unsigned int*)l, 16, 0, 0);
}

// scale 8 consecutive fp32 -> bf16x8 frag
__device__ __forceinline__ bf16x8 frag8(const float* p, float k) {
  float4 f0 = *(const float4*)p, f1 = *(const float4*)(p + 4);
  bf16x8 v;
  v[0] = f2b(f0.x * k); v[1] = f2b(f0.y * k); v[2] = f2b(f0.z * k); v[3] = f2b(f0.w * k);
  v[4] = f2b(f1.x * k); v[5] = f2b(f1.y * k); v[6] = f2b(f1.z * k); v[7] = f2b(f1.w * k);
  return v;
}

// ---------------- merged prep: casts + conv-weight pack ----------------
// blocks [0,8192): x->Xb; [8192,8384): w_qkv; [8384,8448): w_proj; [8448,8704): pack_wc
// Conv weights packed in per-MFMA-fragment LANE order so each B wave-load is ONE
// contiguous 1KB (16 L2 lines fully used, vs 64 lines at 25% with o-major layout):
//   Wc[(((o>>4)*27 + tap)*8 + (i>>5))*512 + (((i>>3)&3)*16 + (o&15))*8 + (i&7)]
//     = w_dwc[o][i][tap]
__global__ void prep_cast(const float* __restrict__ x, const float* __restrict__ wq,
                          const float* __restrict__ wp, const float* __restrict__ wdwc,
                          u16* __restrict__ Xb, u16* __restrict__ Wqb,
                          u16* __restrict__ Wpb, u16* __restrict__ Wc) {
  int b = blockIdx.x, tid = threadIdx.x;
  if (b < 8448) {
    const float* src; u16* dst; int i;
    if (b < 8192)      { src = x;  dst = Xb;  i = b * 256 + tid; }
    else if (b < 8384) { src = wq; dst = Wqb; i = (b - 8192) * 256 + tid; }
    else               { src = wp; dst = Wpb; i = (b - 8384) * 256 + tid; }
    const float4 v = ((const float4*)src)[i];
    uint2 o;
    o.x = (unsigned)f2b(v.x) | ((unsigned)f2b(v.y) << 16);
    o.y = (unsigned)f2b(v.z) | ((unsigned)f2b(v.w) << 16);
    ((uint2*)dst)[i] = o;
  } else {
    int o = b - 8448;                        // output channel o; pack into frag-lane order
    __shared__ u16 lds[6912];
    for (int t = tid; t < 6912; t += 256) lds[t] = f2b(wdwc[o * 6912 + t]);
    __syncthreads();
    int og = o >> 4, r = o & 15;
    for (int idx = tid; idx < 6912; idx += 256) {
      int t = idx >> 8, i = idx & 255;       // t = tap 0..26, i = input chan 0..255
      int panel = i >> 5, q = (i >> 3) & 3, e = i & 7;
      Wc[(((og * 27 + t) * 8 + panel) << 9) + (q * 16 + r) * 8 + e] = lds[i * 27 + t];
    }
  }
}

// ---------------- merged: pad_v + pool_A (both depend only on QKV) ----------------
__global__ void prep_av(const u16* __restrict__ QKV, u16* __restrict__ v5,
                        float* __restrict__ Apre) {
  int b = blockIdx.x, tid = threadIdx.x;
  if (b < 4913) {          // pad_v: V -> padded 34^3 channel-last (halo zeroed)
    int idx = b * 256 + tid;
    int c8 = idx & 31, vox = idx >> 5;
    int z = vox / 1156, r2 = vox - z * 1156, y = r2 / 34, x = r2 - y * 34;
    bf16x8 val = {0, 0, 0, 0, 0, 0, 0, 0};
    if (z >= 1 && z <= 32 && y >= 1 && y <= 32 && x >= 1 && x <= 32) {
      int n = (z - 1) * 1024 + (y - 1) * 32 + (x - 1);
      val = *(const bf16x8*)(QKV + n * 768 + 512 + c8 * 8);
    }
    *(bf16x8*)(v5 + vox * 256 + c8 * 8) = val;
  } else {                 // pool_A partials (faithful torch head-interleave)
    int b2 = b - 4913;
    int a = b2 >> 3, s = b2 & 7;
    int hp = tid >> 5, dp = tid & 31;
    int p1 = a >> 4, p2 = (a >> 2) & 3, p3 = a & 3;
    float sum = 0.f;
    for (int ui = 0; ui < 64; ++ui) {
      int u = s * 64 + ui;
      int f1 = p1 * 8 + (u >> 6);
      int f2 = p2 * 8 + ((u >> 3) & 7);
      int f3 = p3 * 8 + (u & 7);
      int vox = f1 * 1024 + f2 * 32 + f3;
      int n  = ((vox & 4095) << 3) + hp;
      int cq = ((vox >> 12) << 5) + dp;
      sum += b2f(QKV[n * 768 + cq]);
    }
    atomicAdd(&Apre[(hp * 64 + a) * 32 + dp], sum);
  }
}

// ---------------- bf16 NT-GEMM pieces: BK=64 (two 32-K panels), conflict-free LDS --------

__device__ __forceinline__ void stage64(const u16* src, int row0, int ld, int k0,
                                        short* dst, int tid) {
  int wv = tid >> 6, lane = tid & 63;
  int r15 = lane & 15, kc8 = (lane >> 4) * 8;
#pragma unroll
  for (int j = 0; j < 4; ++j) {
    int p = j & 1, g = wv * 2 + (j >> 1);
    async16(src + (row0 + g * 16 + r15) * ld + k0 + p * 32 + kc8, dst + p * 4096 + g * 512);
  }
}

__device__ __forceinline__ void mfma64(const short* As, const short* Bs, int wm, int wn,
                                       int lane, f32x4 acc[4][4]) {
  const int q = lane >> 4, c = lane & 15;
  const int fo = q * 128 + c * 8;
#pragma unroll
  for (int p = 0; p < 2; ++p) {
    bf16x8 a[4], b[4];
#pragma unroll
    for (int mt = 0; mt < 4; ++mt) a[mt] = *(const bf16x8*)&As[p * 4096 + (wm * 4 + mt) * 512 + fo];
#pragma unroll
    for (int nt = 0; nt < 4; ++nt) b[nt] = *(const bf16x8*)&Bs[p * 4096 + (wn * 4 + nt) * 512 + fo];
#pragma unroll
    for (int mt = 0; mt < 4; ++mt)
#pragma unroll
      for (int nt = 0; nt < 4; ++nt)
        acc[mt][nt] = __builtin_amdgcn_mfma_f32_16x16x32_bf16(a[mt], b[nt], acc[mt][nt], 0, 0, 0);
  }
}

// QKV = Xb @ Wq^T + b, bf16 out (32768 x 768)
__global__ __launch_bounds__(256) void gemm_qkv(const u16* __restrict__ Xb,
                                                const u16* __restrict__ Wq,
                                                const float* __restrict__ bias,
                                                u16* __restrict__ QKV) {
  const int m0 = blockIdx.x * 128, n0 = blockIdx.y * 128;
  const int tid = threadIdx.x, lane = tid & 63, wv = tid >> 6;
  const int wm = wv >> 1, wn = wv & 1, q = lane >> 4, c = lane & 15;
  __shared__ short As[8192], Bs[8192];
  f32x4 acc[4][4] = {};
  for (int kb = 0; kb < 256; kb += 64) {
    stage64(Xb, m0, 256, kb, As, tid);
    stage64(Wq, n0, 256, kb, Bs, tid);
    __syncthreads();
    mfma64(As, Bs, wm, wn, lane, acc);
    __syncthreads();
  }
#pragma unroll
  for (int nt = 0; nt < 4; ++nt) {
    int col = n0 + wn * 64 + nt * 16 + c;
    float bv = bias[col];
#pragma unroll
    for (int mt = 0; mt < 4; ++mt) {
      int row = m0 + wm * 64 + mt * 16 + q * 4;
#pragma unroll
      for (int r = 0; r < 4; ++r) QKV[(row + r) * 768 + col] = f2b(acc[mt][nt][r] + bv);
    }
  }
}

// ---------------- conv (R7 champion structure + packed-B addressing) ----------
// R9 post-mortem: conv is L2-LINE-bound, not useful-bytes-bound.  Old o-major B layout
// made each 1KB B wave-load touch 64 lines at 25% use (4x amplification; B = 74% of
// staged bytes).  With the frag-packed Wc each B load is one contiguous 1KB.
// Line traffic/iter: 9KB(A) + 24KB(B) vs 9 + 96 before.  Grid/LDS/loop unchanged:
// 512 blocks, 33792 B, 2 blocks/CU (R9 showed 1 block/CU loses latency cover).
__global__ __launch_bounds__(256) void conv_k(const u16* __restrict__ v5,
                                              const u16* __restrict__ Wc,
                                              const float* __restrict__ bias,
                                              u16* __restrict__ Xp) {
  extern __shared__ char smem[];
  const int tid = threadIdx.x, lane = tid & 63, wv = tid >> 6;
  const int q = lane >> 4, c = lane & 15;
  const int bid = blockIdx.x;
  const int xcd = bid & 7, idx = bid >> 3;
  const int n0 = (idx & 1) * 128;
  const int mt_i = xcd * 32 + (idx >> 1);      // m-tile 0..255
  const int m0 = mt_i * 128;
  const int z0 = mt_i >> 3, y0 = (mt_i & 7) * 4;
  const int wm = wv >> 1, wn = wv & 1;
  const int r15 = lane & 15, kq8 = (lane >> 4) * 8;
  const int og0 = n0 >> 4;                     // weight o-group base (0 or 8)
  const int lane8 = lane << 3;
  short* As = (short*)smem;            // 9 groups * 512 shorts = 9216 B
  short* Bs = (short*)(smem + 9216);   // 3 dx * 8 groups * 512 = 24576 B
  f32x4 acc[4][4] = {};
  for (int dzy = 0; dzy < 9; ++dzy) {
    int dz = dzy / 3, dy = dzy - dz * 3;
    int base = (z0 + dz) * 1156 + (y0 + dy) * 34;
    int tap0 = dzy * 3;
    for (int panel = 0; panel < 8; ++panel) {
      int choff = panel * 32 + kq8;
      for (int g = wv; g < 9; g += 4) {
        int row = base + g * 16 + r15;
        row = row < 39303 ? row : 39303;           // clamp tail (garbage, never read)
        async16(v5 + row * 256 + choff, As + g * 512);
      }
#pragma unroll
      for (int i = wv; i < 24; i += 4) {
        int dx = i >> 3, g = i & 7;                // contiguous 1KB fragment load
        async16(Wc + ((((og0 + g) * 27 + tap0 + dx) * 8 + panel) << 9) + lane8, Bs + i * 512);
      }
      __syncthreads();
#pragma unroll
      for (int dx = 0; dx < 3; ++dx) {
        bf16x8 a[4], b[4];
#pragma unroll
        for (int mt = 0; mt < 4; ++mt) {
          int M = wm * 64 + mt * 16 + c;
          int vx = M + 2 * (M >> 5) + dx;
          a[mt] = *(const bf16x8*)&As[(vx >> 4) * 512 + q * 128 + (vx & 15) * 8];
        }
#pragma unroll
        for (int nt = 0; nt < 4; ++nt)
          b[nt] = *(const bf16x8*)&Bs[dx * 4096 + (wn * 4 + nt) * 512 + q * 128 + c * 8];
#pragma unroll
        for (int mt = 0; mt < 4; ++mt)
#pragma unroll
          for (int nt = 0; nt < 4; ++nt)
            acc[mt][nt] = __builtin_amdgcn_mfma_f32_16x16x32_bf16(a[mt], b[nt], acc[mt][nt], 0, 0, 0);
      }
      __syncthreads();
    }
  }
#pragma unroll
  for (int nt = 0; nt < 4; ++nt) {
    int col = n0 + wn * 64 + nt * 16 + c;
    float bv = bias[col];
#pragma unroll
    for (int mt = 0; mt < 4; ++mt) {
      int row = m0 + wm * 64 + mt * 16 + q * 4;
#pragma unroll
      for (int r = 0; r < 4; ++r) Xp[(row + r) * 256 + col] = f2b(acc[mt][nt][r] + bv);
    }
  }
}

// ---------------- s1_attn (unchanged) ----------
// 1024 blocks (8 heads x 128 chunks of 256 tokens), 50688 B LDS -> 3 blocks/CU.
__global__ __launch_bounds__(256) void s1_k(const u16* __restrict__ QKV,
                                            const float* __restrict__ Apre,
                                            float* __restrict__ avac,
                                            float* __restrict__ rsum) {
  extern __shared__ char smem[];
  const int tid = threadIdx.x, lane = tid & 63, wv = tid >> 6;
  const int q = lane >> 4, c = lane & 15;
  const int vb = blockIdx.x;                 // 0..1023: h = vb>>7 in [0,8)
  const int h = vb >> 7, n0 = (vb & 127) * 256;
  u16* E  = (u16*)smem;            // [64 agents][264] bf16 (pitch-padded)
  u16* VT = (u16*)(smem + 33792);  // [32 d][264] bf16
  float* RED = (float*)smem;       // overlay after E consumed: [4 waves][2048]
  { // stage V chunk transposed: VT[d][tok_local]
    const u16* vrow = QKV + (n0 + tid) * 768 + 512 + h * 32;
#pragma unroll
    for (int d8 = 0; d8 < 4; ++d8) {
      bf16x8 v = *(const bf16x8*)(vrow + d8 * 8);
#pragma unroll
      for (int e = 0; e < 8; ++e) VT[(d8 * 8 + e) * 264 + tid] = (u16)v[e];
    }
  }
  { // QK^T (M=64 agents, N=64 tokens per wave, K=32) + exp -> E
    bf16x8 af[4], bf[4];
#pragma unroll
    for (int mt = 0; mt < 4; ++mt)
      af[mt] = frag8(Apre + h * 2048 + (mt * 16 + c) * 32 + q * 8, KSCALE);
#pragma unroll
    for (int nt = 0; nt < 4; ++nt)
      bf[nt] = *(const bf16x8*)(QKV + (n0 + wv * 64 + nt * 16 + c) * 768 + 256 + h * 32 + q * 8);
#pragma unroll
    for (int mt = 0; mt < 4; ++mt)
#pragma unroll
      for (int nt = 0; nt < 4; ++nt) {
        f32x4 s = {0.f, 0.f, 0.f, 0.f};
        s = __builtin_amdgcn_mfma_f32_16x16x32_bf16(af[mt], bf[nt], s, 0, 0, 0);
#pragma unroll
        for (int r = 0; r < 4; ++r) {
          int a = mt * 16 + q * 4 + r, nl = wv * 64 + nt * 16 + c;
          E[a * 264 + nl] = f2b(__expf(s[r]));
        }
      }
  }
  __syncthreads();
  { // row sums of E (denominator partials)
    int a = tid >> 2, seg = tid & 3;
    float sum = 0.f;
    for (int i = 0; i < 64; ++i) sum += b2f(E[a * 264 + seg * 64 + i]);
    sum += __shfl_xor(sum, 1);
    sum += __shfl_xor(sum, 2);
    if (seg == 0) atomicAdd(&rsum[h * 64 + a], sum);
  }
  // PV: each wave reduces its own 64-token K-slab (M=64 agents, N=32 d)
  f32x4 pv[4][2] = {};
#pragma unroll
  for (int ks = 0; ks < 2; ++ks) {
    bf16x8 ap[4], bp[2];
#pragma unroll
    for (int mt = 0; mt < 4; ++mt)
      ap[mt] = *(const bf16x8*)&E[(mt * 16 + c) * 264 + wv * 64 + ks * 32 + q * 8];
#pragma unroll
    for (int nt = 0; nt < 2; ++nt)
      bp[nt] = *(const bf16x8*)&VT[(nt * 16 + c) * 264 + wv * 64 + ks * 32 + q * 8];
#pragma unroll
    for (int mt = 0; mt < 4; ++mt)
#pragma unroll
      for (int nt = 0; nt < 2; ++nt)
        pv[mt][nt] = __builtin_amdgcn_mfma_f32_16x16x32_bf16(ap[mt], bp[nt], pv[mt][nt], 0, 0, 0);
  }
  __syncthreads();            // all E/VT reads done; reuse smem as RED
#pragma unroll
  for (int mt = 0; mt < 4; ++mt)
#pragma unroll
    for (int nt = 0; nt < 2; ++nt)
#pragma unroll
      for (int r = 0; r < 4; ++r)
        RED[wv * 2048 + (mt * 16 + q * 4 + r) * 32 + nt * 16 + c] = pv[mt][nt][r];
  __syncthreads();
  for (int idx = tid; idx < 2048; idx += 256) {
    float t = RED[idx] + RED[2048 + idx] + RED[4096 + idx] + RED[6144 + idx];
    atomicAdd(&avac[h * 2048 + idx], t);
  }
}

// out = Xp @ Wp^T + b_proj, fp32 out (32768 x 256)
__global__ __launch_bounds__(256) void gemm_proj(const u16* __restrict__ Xp,
                                                 const u16* __restrict__ Wp,
                                                 const float* __restrict__ bias,
                                                 float* __restrict__ out) {
  const int m0 = blockIdx.x * 128, n0 = blockIdx.y * 128;
  const int tid = threadIdx.x, lane = tid & 63, wv = tid >> 6;
  const int wm = wv >> 1, wn = wv & 1, q = lane >> 4, c = lane & 15;
  __shared__ short As[8192], Bs[8192];
  f32x4 acc[4][4] = {};
  for (int kb = 0; kb < 256; kb += 64) {
    stage64(Xp, m0, 256, kb, As, tid);
    stage64(Wp, n0, 256, kb, Bs, tid);
    __syncthreads();
    mfma64(As, Bs, wm, wn, lane, acc);
    __syncthreads();
  }
#pragma unroll
  for (int nt = 0; nt < 4; ++nt) {
    int col = n0 + wn * 64 + nt * 16 + c;
    float bv = bias[col];
#pragma unroll
    for (int mt = 0; mt < 4; ++mt) {
      int row = m0 + wm * 64 + mt * 16 + q * 4;
#pragma unroll
      for (int r = 0; r < 4; ++r) out[(row + r) * 256 + col] = acc[mt][nt][r] + bv;
    }
  }
}

// ---------------- stage-2: queries attend agents; normalize agent_v in-preamble ----------
__global__ __launch_bounds__(256) void s2_attn(const u16* __restrict__ QKV,
                                               const float* __restrict__ Apre,
                                               const float* __restrict__ avac,
                                               const float* __restrict__ rsum,
                                               u16* __restrict__ Xp) {
  const int h = blockIdx.y, n0 = blockIdx.x * 256;
  const int tid = threadIdx.x, lane = tid & 63, wv = tid >> 6;
  const int q = lane >> 4, c = lane & 15;
  extern __shared__ char smem[];
  u16* P = (u16*)smem;                  // [256 tok][72] bf16 (36864 B)
  float* O = (float*)smem;              // overlay later: [32 d][258] f32 (33024 B)
  u16* AVT = (u16*)(smem + 36864);      // [32 d][72 pitch] bf16 normalized agent_v

  // fold s1_norm: normalize+transpose agent_v for this head into LDS
  for (int j = 0; j < 8; ++j) {
    int i = j * 256 + tid;              // i = a*32 + d
    int a = i >> 5, d = i & 31;
    AVT[d * 72 + a] = f2b(avac[h * 2048 + i] / rsum[h * 64 + a]);
  }

  f32x4 s[4][4];
  { // QK^T: M=64 tokens/wave, N=64 agents, K=32
    bf16x8 af[4], bf[4];
#pragma unroll
    for (int mt = 0; mt < 4; ++mt)
      af[mt] = *(const bf16x8*)(QKV + (n0 + wv * 64 + mt * 16 + c) * 768 + h * 32 + q * 8);
#pragma unroll
    for (int nt = 0; nt < 4; ++nt)
      bf[nt] = frag8(Apre + h * 2048 + (nt * 16 + c) * 32 + q * 8, KSCALE);
#pragma unroll
    for (int mt = 0; mt < 4; ++mt)
#pragma unroll
      for (int nt = 0; nt < 4; ++nt) {
        f32x4 z = {0.f, 0.f, 0.f, 0.f};
        s[mt][nt] = __builtin_amdgcn_mfma_f32_16x16x32_bf16(af[mt], bf[nt], z, 0, 0, 0);
      }
  }
  // softmax across 64 agents per token row: 4 reg-values + shfl over 16-lane col group
#pragma unroll
  for (int mt = 0; mt < 4; ++mt)
#pragma unroll
    for (int r = 0; r < 4; ++r) {
      float v0 = s[mt][0][r], v1 = s[mt][1][r], v2 = s[mt][2][r], v3 = s[mt][3][r];
      float mx = fmaxf(fmaxf(v0, v1), fmaxf(v2, v3));
      mx = fmaxf(mx, __shfl_xor(mx, 1));
      mx = fmaxf(mx, __shfl_xor(mx, 2));
      mx = fmaxf(mx, __shfl_xor(mx, 4));
      mx = fmaxf(mx, __shfl_xor(mx, 8));
      float e0 = __expf(v0 - mx), e1 = __expf(v1 - mx), e2 = __expf(v2 - mx), e3 = __expf(v3 - mx);
      float sm = e0 + e1 + e2 + e3;
      sm += __shfl_xor(sm, 1);
      sm += __shfl_xor(sm, 2);
      sm += __shfl_xor(sm, 4);
      sm += __shfl_xor(sm, 8);
      float inv = 1.0f / sm;
      int tok = wv * 64 + mt * 16 + q * 4 + r;
      P[tok * 72 +      c] = f2b(e0 * inv);
      P[tok * 72 + 16 + c] = f2b(e1 * inv);
      P[tok * 72 + 32 + c] = f2b(e2 * inv);
      P[tok * 72 + 48 + c] = f2b(e3 * inv);
    }
  __syncthreads();   // also fences the AVT preamble writes
  // PV: O = P(64x64) @ agent_v(64x32); AVT is [d][a] in LDS (K=a contiguous)
  f32x4 o[4][2] = {};
#pragma unroll
  for (int ks = 0; ks < 2; ++ks) {
    bf16x8 ap[4], bv[2];
#pragma unroll
    for (int mt = 0; mt < 4; ++mt)
      ap[mt] = *(const bf16x8*)&P[(wv * 64 + mt * 16 + c) * 72 + ks * 32 + q * 8];
#pragma unroll
    for (int nt = 0; nt < 2; ++nt)
      bv[nt] = *(const bf16x8*)&AVT[(nt * 16 + c) * 72 + ks * 32 + q * 8];
#pragma unroll
    for (int mt = 0; mt < 4; ++mt)
#pragma unroll
      for (int nt = 0; nt < 2; ++nt)
        o[mt][nt] = __builtin_amdgcn_mfma_f32_16x16x32_bf16(ap[mt], bv[nt], o[mt][nt], 0, 0, 0);
  }
  __syncthreads();  // P reads done; reuse smem as O
#pragma unroll
  for (int mt = 0; mt < 4; ++mt)
#pragma unroll
    for (int nt = 0; nt < 2; ++nt)
#pragma unroll
      for (int r = 0; r < 4; ++r)
        O[(nt * 16 + c) * 258 + wv * 64 + mt * 16 + q * 4 + r] = o[mt][nt][r];
  __syncthreads();
  // coalesced RMW: flat offset (h*32+d)*32768 + n == row-major (n',c') of the torch reshape
  for (int d = 0; d < 32; ++d) {
    int addr = (h * 32 + d) * 32768 + n0 + tid;
    Xp[addr] = f2b(b2f(Xp[addr]) + O[d * 258 + tid]);
  }
}

// ---------------- launch ----------------

extern "C" void kernel_launch(void* const* d_in, const int* in_sizes, int n_in,
                              void* d_out, int out_size, void* d_ws, size_t ws_size,
                              hipStream_t stream) {
  const float* x      = (const float*)d_in[0];
  const float* w_qkv  = (const float*)d_in[1];
  const float* b_qkv  = (const float*)d_in[2];
  const float* w_proj = (const float*)d_in[3];
  const float* b_proj = (const float*)d_in[4];
  const float* w_dwc  = (const float*)d_in[5];
  const float* b_dwc  = (const float*)d_in[6];
  float* out = (float*)d_out;
  char* ws = (char*)d_ws;

  u16* Xb   = (u16*)(ws);              // 16 MB; conv writes Xp here (x-cast dead by then)
  u16* QKV  = (u16*)(ws + 16777216);   // 48 MB bf16 (32768 x 768)
  u16* V5   = (u16*)(ws + 67108864);   // 20.1 MB padded volume
  u16* Wc   = (u16*)(ws + 87232512);   // 3.5 MB conv weights, frag-packed
  u16* Wqb  = (u16*)(ws + 90771456);
  u16* Wpb  = (u16*)(ws + 91164672);
  float* AVAC = (float*)(ws + 91361280);   // 64 KB
  float* RSUM = (float*)(ws + 91426816);   // 2 KB
  float* APRE = (float*)(ws + 91428864);   // 64 KB
  u16* Xp = Xb;

  hipMemsetAsync(AVAC, 0, 65536 + 2048 + 65536, stream);  // AVAC+RSUM+APRE contiguous
  prep_cast<<<8704, 256, 0, stream>>>(x, w_qkv, w_proj, w_dwc, Xb, Wqb, Wpb, Wc);
  gemm_qkv<<<dim3(256, 6), 256, 0, stream>>>(Xb, Wqb, b_qkv, QKV);
  prep_av<<<5425, 256, 0, stream>>>(QKV, V5, APRE);
  conv_k<<<512, 256, 33792, stream>>>(V5, Wc, b_dwc, Xp);
  s1_k<<<1024, 256, 50688, stream>>>(QKV, APRE, AVAC, RSUM);
  s2_attn<<<dim3(128, 8), 256, 41472, stream>>>(QKV, APRE, AVAC, RSUM, Xp);
  gemm_proj<<<dim3(256, 2), 256, 0, stream>>>(Xp, Wpb, b_proj, out);
}